// Round 2
// baseline (232.221 us; speedup 1.0000x reference)
//
#include <hip/hip_runtime.h>
#include <hip/hip_bf16.h>
#include <stdint.h>

typedef __attribute__((ext_vector_type(8))) short bf16x8;
typedef __attribute__((ext_vector_type(4))) float f32x4;
typedef __attribute__((ext_vector_type(8))) unsigned short ushort8;

__device__ __forceinline__ unsigned short f2bf(float f) {
  unsigned int u = __float_as_uint(f);
  unsigned int r = (u + 0x7FFFu + ((u >> 16) & 1u)) >> 16;  // RNE
  return (unsigned short)r;
}

__device__ __forceinline__ void gld_lds16(const void* g, void* l) {
  __builtin_amdgcn_global_load_lds(
      (const __attribute__((address_space(1))) unsigned int*)g,
      (__attribute__((address_space(3))) unsigned int*)l,
      16, 0, 0);
}

// ---------------- cast x (fp32 -> bf16), 8 elems/thread ----------------
__global__ void cast_x_kernel(const float* __restrict__ x,
                              unsigned short* __restrict__ xb, int n8) {
  int i = blockIdx.x * blockDim.x + threadIdx.x;
  if (i >= n8) return;
  const float4* xp = (const float4*)x + (long)i * 2;
  float4 a = xp[0];
  float4 b = xp[1];
  ushort8 o;
  o[0] = f2bf(a.x); o[1] = f2bf(a.y); o[2] = f2bf(a.z); o[3] = f2bf(a.w);
  o[4] = f2bf(b.x); o[5] = f2bf(b.y); o[6] = f2bf(b.z); o[7] = f2bf(b.w);
  *((ushort8*)xb + i) = o;
}

// ---------------- cast + transpose W: wt[n][k] = bf16(W[k][n]) ----------------
__global__ void cast_wt_kernel(const float* __restrict__ W,
                               unsigned short* __restrict__ wt) {
  int t = blockIdx.x * blockDim.x + threadIdx.x;  // 512*512 threads
  int n = t >> 9;
  int k = t & 511;
  wt[t] = f2bf(W[k * 512 + n]);
}

// ---------------- fused GEMM + bias + relu + LN-stats ----------------
// h = relu(x @ W + b), per (row, head=ntile) mean & rstd over the 128 cols.
// Tile 128x128, BK=32, 4 waves (2x2), mfma_f32_16x16x32_bf16, 4x4 frags/wave.
// LDS tiles [128 rows][32 k] bf16, row stride 64B, 16B-slot XOR swizzle:
//   off(row,k8) = row*64 + ((k8 ^ ((row>>1)&3))*16)   -> max 2-way bank alias.
__global__ __launch_bounds__(256, 2) void gemm_ln_kernel(
    const unsigned short* __restrict__ xb,   // [N][512] bf16
    const unsigned short* __restrict__ wt,   // [512][512] bf16 (W^T)
    const float* __restrict__ bias,          // [512]
    float* __restrict__ h,                   // [N][512] fp32
    float* __restrict__ mu,                  // [N][4]
    float* __restrict__ rstd,                // [N][4]
    int N) {
  __shared__ __align__(16) unsigned short As[128 * 32];
  __shared__ __align__(16) unsigned short Bs[128 * 32];
  __shared__ float redS[128 * 2];
  __shared__ float redQ[128 * 2];

  const int bid = blockIdx.x;
  const int mtile = bid >> 2;
  const int ntile = bid & 3;          // == LN head index
  const int m0 = mtile << 7;
  const int n0 = ntile << 7;

  const int tid = threadIdx.x;
  const int lane = tid & 63;
  const int wid = tid >> 6;
  const int wr = wid >> 1;
  const int wc = wid & 1;

  f32x4 acc[4][4];
#pragma unroll
  for (int m = 0; m < 4; m++)
#pragma unroll
    for (int n = 0; n < 4; n++) acc[m][n] = (f32x4){0.f, 0.f, 0.f, 0.f};

  // staging geometry: chunk c covers LDS bytes [c*1024, c*1024+1024), lane*16 within
  const int pA0 = (wid * 2 + 0) * 1024 + lane * 16;
  const int pA1 = (wid * 2 + 1) * 1024 + lane * 16;
  const int rowS0 = pA0 >> 6, rowS1 = pA1 >> 6;
  const int k8S0 = ((pA0 >> 4) & 3) ^ ((rowS0 >> 1) & 3);
  const int k8S1 = ((pA1 >> 4) & 3) ^ ((rowS1 >> 1) & 3);
  const long gA0 = (long)min(m0 + rowS0, N - 1) * 512 + k8S0 * 8;
  const long gA1 = (long)min(m0 + rowS1, N - 1) * 512 + k8S1 * 8;
  const long gB0 = (long)(n0 + rowS0) * 512 + k8S0 * 8;
  const long gB1 = (long)(n0 + rowS1) * 512 + k8S1 * 8;
  char* AsB = (char*)As;
  char* BsB = (char*)Bs;
  const int ldsC0 = (wid * 2 + 0) * 1024;  // wave-uniform LDS chunk bases
  const int ldsC1 = (wid * 2 + 1) * 1024;

  // fragment read offsets (swizzled)
  const int rsel = lane & 15;
  const int k8l = lane >> 4;
  int offA[4], offB[4];
#pragma unroll
  for (int m = 0; m < 4; m++) {
    int ra = wr * 64 + m * 16 + rsel;
    offA[m] = ra * 64 + ((k8l ^ ((ra >> 1) & 3)) << 4);
    int rb = wc * 64 + m * 16 + rsel;
    offB[m] = rb * 64 + ((k8l ^ ((rb >> 1) & 3)) << 4);
  }

  for (int k0 = 0; k0 < 512; k0 += 32) {
    gld_lds16(xb + gA0 + k0, AsB + ldsC0);
    gld_lds16(xb + gA1 + k0, AsB + ldsC1);
    gld_lds16(wt + gB0 + k0, BsB + ldsC0);
    gld_lds16(wt + gB1 + k0, BsB + ldsC1);
    __syncthreads();
    bf16x8 af[4], bfr[4];
#pragma unroll
    for (int m = 0; m < 4; m++) af[m] = *(const bf16x8*)(AsB + offA[m]);
#pragma unroll
    for (int n = 0; n < 4; n++) bfr[n] = *(const bf16x8*)(BsB + offB[n]);
#pragma unroll
    for (int m = 0; m < 4; m++)
#pragma unroll
      for (int n = 0; n < 4; n++)
        acc[m][n] = __builtin_amdgcn_mfma_f32_16x16x32_bf16(af[m], bfr[n],
                                                            acc[m][n], 0, 0, 0);
    __syncthreads();
  }

  // ---- epilogue: bias + relu, store h, per-row sum/sumsq over this head ----
  const int colb = n0 + wc * 64 + rsel;  // this lane's column (+ n*16)
  float bval[4];
#pragma unroll
  for (int n = 0; n < 4; n++) bval[n] = bias[colb + n * 16];

#pragma unroll
  for (int m = 0; m < 4; m++) {
    const int rbase = wr * 64 + m * 16 + ((lane >> 4) << 2);
#pragma unroll
    for (int i = 0; i < 4; i++) {
      const int row_l = rbase + i;
      const long row_g = (long)m0 + row_l;
      const bool valid = row_g < N;
      float s = 0.f, q = 0.f;
#pragma unroll
      for (int n = 0; n < 4; n++) {
        float v = acc[m][n][i] + bval[n];
        v = fmaxf(v, 0.f);
        s += v;
        q += v * v;
        if (valid) h[row_g * 512 + colb + n * 16] = v;
      }
#pragma unroll
      for (int d = 1; d < 16; d <<= 1) {
        s += __shfl_xor(s, d, 64);
        q += __shfl_xor(q, d, 64);
      }
      if (rsel == 0) {
        redS[row_l * 2 + wc] = s;
        redQ[row_l * 2 + wc] = q;
      }
    }
  }
  __syncthreads();
  if (tid < 128) {
    const long row_g = (long)m0 + tid;
    if (row_g < N) {
      float s = redS[tid * 2] + redS[tid * 2 + 1];
      float q = redQ[tid * 2] + redQ[tid * 2 + 1];
      float mean = s * (1.f / 128.f);
      float var = q * (1.f / 128.f) - mean * mean;
      mu[row_g * 4 + ntile] = mean;
      rstd[row_g * 4 + ntile] = rsqrtf(var + 1e-5f);
    }
  }
}

// ---------------- per-graph online segment softmax + weighted pooling ----------------
__global__ __launch_bounds__(512) void pool_kernel(
    const float* __restrict__ h, const float* __restrict__ mu,
    const float* __restrict__ rstd, const float* __restrict__ qs,
    const int* __restrict__ gidx, float* __restrict__ out, int N) {
  const int g = blockIdx.x;
  const int ch = threadIdx.x;

  // lower_bound(g), lower_bound(g+1) over sorted gidx — uniform across block
  int lo = 0, hi = N;
  while (lo < hi) {
    int mid = (lo + hi) >> 1;
    if (gidx[mid] < g) lo = mid + 1; else hi = mid;
  }
  const int s0 = lo;
  hi = N;
  while (lo < hi) {
    int mid = (lo + hi) >> 1;
    if (gidx[mid] < g + 1) lo = mid + 1; else hi = mid;
  }
  const int e0 = lo;

  const float qscale = qs[ch];
  const int head = ch >> 7;
  float m = -INFINITY, S = 0.f, Nm = 0.f;

  int n = s0;
  for (; n + 4 <= e0; n += 4) {
    float hv[4], muv[4], rsv[4];
#pragma unroll
    for (int j = 0; j < 4; j++) {
      hv[j] = h[(long)(n + j) * 512 + ch];
      muv[j] = mu[(n + j) * 4 + head];
      rsv[j] = rstd[(n + j) * 4 + head];
    }
#pragma unroll
    for (int j = 0; j < 4; j++) {
      float qv = (hv[j] - muv[j]) * rsv[j] * qscale;
      float nm = fmaxf(m, qv);
      float c = __expf(m - nm);
      float p = __expf(qv - nm);
      S = S * c + p;
      Nm = Nm * c + p * hv[j];
      m = nm;
    }
  }
  for (; n < e0; ++n) {
    float hv = h[(long)n * 512 + ch];
    float qv = (hv - mu[n * 4 + head]) * rstd[n * 4 + head] * qscale;
    float nm = fmaxf(m, qv);
    float c = __expf(m - nm);
    float p = __expf(qv - nm);
    S = S * c + p;
    Nm = Nm * c + p * hv;
    m = nm;
  }
  out[g * 512 + ch] = Nm / (S + 1e-16f);
}

extern "C" void kernel_launch(void* const* d_in, const int* in_sizes, int n_in,
                              void* d_out, int out_size, void* d_ws, size_t ws_size,
                              hipStream_t stream) {
  const float* x = (const float*)d_in[0];
  const float* W = (const float*)d_in[1];
  const float* bias = (const float*)d_in[2];
  const float* qs = (const float*)d_in[3];
  const int* gidx = (const int*)d_in[4];
  const int N = in_sizes[0] / 512;
  const int B = out_size / 512;
  float* out = (float*)d_out;

  char* ws = (char*)d_ws;
  size_t off = 0;
  auto alloc = [&](size_t bytes) {
    char* p = ws + off;
    off += (bytes + 255) & ~(size_t)255;
    return p;
  };
  unsigned short* xb = (unsigned short*)alloc((size_t)N * 512 * 2);
  unsigned short* wt = (unsigned short*)alloc((size_t)512 * 512 * 2);
  float* h = (float*)alloc((size_t)N * 512 * 4);
  float* mu = (float*)alloc((size_t)N * 4 * 4);
  float* rstd = (float*)alloc((size_t)N * 4 * 4);
  (void)ws_size;  // need ~311 MB

  const int n8 = N * 512 / 8;
  cast_x_kernel<<<(n8 + 255) / 256, 256, 0, stream>>>(x, xb, n8);
  cast_wt_kernel<<<(512 * 512) / 256, 256, 0, stream>>>(W, wt);
  const int mtiles = (N + 127) / 128;
  gemm_ln_kernel<<<mtiles * 4, 256, 0, stream>>>(xb, wt, bias, h, mu, rstd, N);
  pool_kernel<<<B, 512, 0, stream>>>(h, mu, rstd, qs, gidx, out, N);
}

// Round 3
// 172.940 us; speedup vs baseline: 1.3428x; 1.3428x over previous
//
#include <hip/hip_runtime.h>
#include <hip/hip_bf16.h>
#include <stdint.h>

typedef __attribute__((ext_vector_type(8))) short bf16x8;
typedef __attribute__((ext_vector_type(4))) float f32x4;
typedef __attribute__((ext_vector_type(8))) unsigned short ushort8;

__device__ __forceinline__ unsigned short f2bf(float f) {
  unsigned int u = __float_as_uint(f);
  unsigned int r = (u + 0x7FFFu + ((u >> 16) & 1u)) >> 16;  // RNE
  return (unsigned short)r;
}

__device__ __forceinline__ void gld_lds16(const void* g, void* l) {
  __builtin_amdgcn_global_load_lds(
      (const __attribute__((address_space(1))) unsigned int*)g,
      (__attribute__((address_space(3))) unsigned int*)l,
      16, 0, 0);
}

// ---------------- cast + transpose W: wt[n][k] = bf16(W[k][n]) ----------------
__global__ void cast_wt_kernel(const float* __restrict__ W,
                               unsigned short* __restrict__ wt) {
  int t = blockIdx.x * blockDim.x + threadIdx.x;  // 512*512 threads
  int n = t >> 9;
  int k = t & 511;
  wt[t] = f2bf(W[k * 512 + n]);
}

// ---------------- fused GEMM + bias + relu + LN-stats ----------------
// h = relu(x @ W + b) stored bf16; per (row, head=ntile) mean & rstd (float2).
// Tile 128x128, BK=64, 4 waves (2x2), mfma_f32_16x16x32_bf16, 4x4 frags/wave.
// A: x fp32 read direct, reg-staged + cvt + swizzled ds_write.
// B: wt bf16 via global_load_lds (pre-swizzled global source), double-buffered.
// LDS tiles [128 rows][64 k] bf16, row stride 128B, 16B-slot XOR swizzle:
//   off(row,k8) = row*128 + ((k8 ^ (row&7))*16),  k8 in [0,8).
__global__ __launch_bounds__(256, 2) void gemm_ln_kernel(
    const float* __restrict__ x,             // [N][512] fp32
    const unsigned short* __restrict__ wt,   // [512][512] bf16 (W^T)
    const float* __restrict__ bias,          // [512]
    unsigned short* __restrict__ h,          // [N][512] bf16
    float2* __restrict__ mr,                 // [N][4] (mean, rstd)
    int N, int mtiles) {
  __shared__ __align__(16) unsigned short As[128 * 64];
  __shared__ __align__(16) unsigned short Bs[2][128 * 64];
  __shared__ float redS[128 * 2];
  __shared__ float redQ[128 * 2];

  // ---- XCD-grouped bid remap: 4 ntile-peers of an mtile share bid%8 ----
  const int nfull = (mtiles >> 3) << 3;
  const int full_bids = nfull * 4;
  int mtile, ntile;
  {
    const int bid = blockIdx.x;
    if (bid < full_bids) {
      const int chunk = bid >> 5, j = bid & 31;
      mtile = (chunk << 3) + (j & 7);
      ntile = j >> 3;
    } else {
      const int j = bid - full_bids;
      const int rem = mtiles - nfull;
      mtile = nfull + j % rem;
      ntile = j / rem;
    }
  }
  const int m0 = mtile << 7;
  const int n0 = ntile << 7;

  const int tid = threadIdx.x;
  const int lane = tid & 63;
  const int wid = tid >> 6;
  const int wr = wid >> 1;
  const int wc = wid & 1;

  f32x4 acc[4][4];
#pragma unroll
  for (int m = 0; m < 4; m++)
#pragma unroll
    for (int n = 0; n < 4; n++) acc[m][n] = (f32x4){0.f, 0.f, 0.f, 0.f};

  char* AsB = (char*)As;

  // ---- A staging geometry (reg-staged): 4 iters x 8 elems/thread ----
  const float* aBase[4];
  int aDst[4];
#pragma unroll
  for (int it = 0; it < 4; it++) {
    const int id = it * 256 + tid;   // [0,1024)
    const int row = id >> 3;         // [0,128)
    const int k8 = id & 7;
    aBase[it] = x + (long)min(m0 + row, N - 1) * 512 + k8 * 8;
    aDst[it] = row * 128 + ((k8 ^ (row & 7)) << 4);
  }

  // ---- B staging geometry (gld_lds, pre-swizzled source): 4 lines ----
  const unsigned short* bP[4];
  int bLds[4];  // wave-uniform LDS base per line
#pragma unroll
  for (int L = 0; L < 4; L++) {
    const int p = (L << 12) + tid * 16;
    const int row = p >> 7;
    const int slot = (p >> 4) & 7;
    const int k8 = slot ^ (row & 7);
    bP[L] = wt + (long)(n0 + row) * 512 + k8 * 8;
    bLds[L] = (L << 12) + (wid << 10);
  }

  // ---- fragment read offsets (swizzled), [kk][m] compile-time indexed ----
  const int rsel = lane & 15;
  const int k8l = lane >> 4;
  int offA[2][4], offB[2][4];
#pragma unroll
  for (int kk = 0; kk < 2; kk++)
#pragma unroll
    for (int m = 0; m < 4; m++) {
      const int ra = wr * 64 + m * 16 + rsel;
      offA[kk][m] = ra * 128 + ((((kk << 2) + k8l) ^ (ra & 7)) << 4);
      const int rb = wc * 64 + m * 16 + rsel;
      offB[kk][m] = rb * 128 + ((((kk << 2) + k8l) ^ (rb & 7)) << 4);
    }

  // ---- prologue: B(0) -> Bs[0]; A(0) -> regs ----
#pragma unroll
  for (int L = 0; L < 4; L++) gld_lds16(bP[L], (char*)Bs[0] + bLds[L]);
  float4 ar[4][2];
#pragma unroll
  for (int it = 0; it < 4; it++) {
    const float4* ap = (const float4*)aBase[it];
    ar[it][0] = ap[0];
    ar[it][1] = ap[1];
  }

  for (int t = 0; t < 8; t++) {
    // cvt + ds_write A(t)
#pragma unroll
    for (int it = 0; it < 4; it++) {
      ushort8 o;
      o[0] = f2bf(ar[it][0].x); o[1] = f2bf(ar[it][0].y);
      o[2] = f2bf(ar[it][0].z); o[3] = f2bf(ar[it][0].w);
      o[4] = f2bf(ar[it][1].x); o[5] = f2bf(ar[it][1].y);
      o[6] = f2bf(ar[it][1].z); o[7] = f2bf(ar[it][1].w);
      *(ushort8*)(AsB + aDst[it]) = o;
    }
    __syncthreads();  // As(t), Bs[t&1] ready (drains vmcnt+lgkmcnt)

    if (t < 7) {
      const int k0n = (t + 1) << 6;
      // issue B(t+1) into the other buffer — hidden under MFMA below
#pragma unroll
      for (int L = 0; L < 4; L++)
        gld_lds16(bP[L] + k0n, (char*)Bs[(t + 1) & 1] + bLds[L]);
      // prefetch A(t+1) to regs — hidden under MFMA below
#pragma unroll
      for (int it = 0; it < 4; it++) {
        const float4* ap = (const float4*)(aBase[it] + k0n);
        ar[it][0] = ap[0];
        ar[it][1] = ap[1];
      }
    }

    const char* BsB = (const char*)Bs[t & 1];
#pragma unroll
    for (int kk = 0; kk < 2; kk++) {
      bf16x8 af[4], bq[4];
#pragma unroll
      for (int m = 0; m < 4; m++) af[m] = *(const bf16x8*)(AsB + offA[kk][m]);
#pragma unroll
      for (int n = 0; n < 4; n++) bq[n] = *(const bf16x8*)(BsB + offB[kk][n]);
#pragma unroll
      for (int m = 0; m < 4; m++)
#pragma unroll
        for (int n = 0; n < 4; n++)
          acc[m][n] = __builtin_amdgcn_mfma_f32_16x16x32_bf16(af[m], bq[n],
                                                              acc[m][n], 0, 0, 0);
    }
    __syncthreads();  // all waves done reading As/Bs[t&1]; drains B(t+1) gld
  }

  // ---- epilogue: bias + relu, store h bf16, per-row sum/sumsq ----
  const int colb = n0 + wc * 64 + rsel;
  float bval[4];
#pragma unroll
  for (int n = 0; n < 4; n++) bval[n] = bias[colb + n * 16];

#pragma unroll
  for (int m = 0; m < 4; m++) {
    const int rbase = wr * 64 + m * 16 + ((lane >> 4) << 2);
#pragma unroll
    for (int i = 0; i < 4; i++) {
      const int row_l = rbase + i;
      const long row_g = (long)m0 + row_l;
      const bool valid = row_g < N;
      float s = 0.f, q = 0.f;
#pragma unroll
      for (int n = 0; n < 4; n++) {
        float v = acc[m][n][i] + bval[n];
        v = fmaxf(v, 0.f);
        s += v;
        q += v * v;
        if (valid) h[row_g * 512 + colb + n * 16] = f2bf(v);
      }
#pragma unroll
      for (int d = 1; d < 16; d <<= 1) {
        s += __shfl_xor(s, d, 64);
        q += __shfl_xor(q, d, 64);
      }
      if (rsel == 0) {
        redS[row_l * 2 + wc] = s;
        redQ[row_l * 2 + wc] = q;
      }
    }
  }
  __syncthreads();
  if (tid < 128) {
    const long row_g = (long)m0 + tid;
    if (row_g < N) {
      float s = redS[tid * 2] + redS[tid * 2 + 1];
      float q = redQ[tid * 2] + redQ[tid * 2 + 1];
      float mean = s * (1.f / 128.f);
      float var = q * (1.f / 128.f) - mean * mean;
      mr[row_g * 4 + ntile] = make_float2(mean, rsqrtf(var + 1e-5f));
    }
  }
}

// ---------------- per-graph online segment softmax + weighted pooling ----------------
__global__ __launch_bounds__(512) void pool_kernel(
    const unsigned short* __restrict__ h, const float2* __restrict__ mr,
    const float* __restrict__ qs, const int* __restrict__ gidx,
    float* __restrict__ out, int N) {
  const int g = blockIdx.x;
  const int ch = threadIdx.x;

  // lower_bound(g), lower_bound(g+1) over sorted gidx — uniform across block
  int lo = 0, hi = N;
  while (lo < hi) {
    int mid = (lo + hi) >> 1;
    if (gidx[mid] < g) lo = mid + 1; else hi = mid;
  }
  const int s0 = lo;
  hi = N;
  while (lo < hi) {
    int mid = (lo + hi) >> 1;
    if (gidx[mid] < g + 1) lo = mid + 1; else hi = mid;
  }
  const int e0 = lo;

  const float qscale = qs[ch];
  const int head = ch >> 7;
  float m = -INFINITY, S = 0.f, Nm = 0.f;

  int n = s0;
  for (; n + 4 <= e0; n += 4) {
    float hv[4];
    float2 mv[4];
#pragma unroll
    for (int j = 0; j < 4; j++) {
      hv[j] = __uint_as_float((unsigned int)h[(long)(n + j) * 512 + ch] << 16);
      mv[j] = mr[(long)(n + j) * 4 + head];
    }
#pragma unroll
    for (int j = 0; j < 4; j++) {
      float qv = (hv[j] - mv[j].x) * mv[j].y * qscale;
      float nm = fmaxf(m, qv);
      float c = __expf(m - nm);
      float p = __expf(qv - nm);
      S = S * c + p;
      Nm = Nm * c + p * hv[j];
      m = nm;
    }
  }
  for (; n < e0; ++n) {
    float hv = __uint_as_float((unsigned int)h[(long)n * 512 + ch] << 16);
    float2 mv = mr[(long)n * 4 + head];
    float qv = (hv - mv.x) * mv.y * qscale;
    float nm = fmaxf(m, qv);
    float c = __expf(m - nm);
    float p = __expf(qv - nm);
    S = S * c + p;
    Nm = Nm * c + p * hv;
    m = nm;
  }
  out[g * 512 + ch] = Nm / (S + 1e-16f);
}

extern "C" void kernel_launch(void* const* d_in, const int* in_sizes, int n_in,
                              void* d_out, int out_size, void* d_ws, size_t ws_size,
                              hipStream_t stream) {
  const float* x = (const float*)d_in[0];
  const float* W = (const float*)d_in[1];
  const float* bias = (const float*)d_in[2];
  const float* qs = (const float*)d_in[3];
  const int* gidx = (const int*)d_in[4];
  const int N = in_sizes[0] / 512;
  const int B = out_size / 512;
  float* out = (float*)d_out;

  char* ws = (char*)d_ws;
  size_t off = 0;
  auto alloc = [&](size_t bytes) {
    char* p = ws + off;
    off += (bytes + 255) & ~(size_t)255;
    return p;
  };
  unsigned short* wt = (unsigned short*)alloc((size_t)512 * 512 * 2);
  unsigned short* h = (unsigned short*)alloc((size_t)N * 512 * 2);
  float2* mr = (float2*)alloc((size_t)N * 4 * sizeof(float2));
  (void)ws_size;  // need ~106 MB

  cast_wt_kernel<<<(512 * 512) / 256, 256, 0, stream>>>(W, wt);
  const int mtiles = (N + 127) / 128;
  gemm_ln_kernel<<<mtiles * 4, 256, 0, stream>>>(x, wt, bias, h, mr, N, mtiles);
  pool_kernel<<<B, 512, 0, stream>>>(h, mr, qs, gidx, out, N);
}